// Round 1
// baseline (309.034 us; speedup 1.0000x reference)
//
#include <hip/hip_runtime.h>
#include <hip/hip_bf16.h>
#include <stdint.h>

#define N_TOK 4096
#define DIM   512
#define BATCH 4

typedef __attribute__((ext_vector_type(8))) short bf16x8;
typedef __attribute__((ext_vector_type(4))) float f32x4;

// ---------- kernel 1: per-row sum-of-squares (fp32) + fp32->bf16 convert ----------
__global__ __launch_bounds__(256) void prep_kernel(
    const float* __restrict__ feat, ushort* __restrict__ fb, float* __restrict__ sq)
{
    int wave = (blockIdx.x << 2) + (threadIdx.x >> 6);   // row index 0..B*N-1
    int lane = threadIdx.x & 63;
    const float4* src = (const float4*)(feat + (size_t)wave * DIM);
    float4 v0 = src[lane * 2];
    float4 v1 = src[lane * 2 + 1];
    float s = v0.x*v0.x + v0.y*v0.y + v0.z*v0.z + v0.w*v0.w
            + v1.x*v1.x + v1.y*v1.y + v1.z*v1.z + v1.w*v1.w;

    float vv[8] = {v0.x, v0.y, v0.z, v0.w, v1.x, v1.y, v1.z, v1.w};
    ushort h[8];
#pragma unroll
    for (int i = 0; i < 8; ++i) {         // RNE fp32->bf16
        uint32_t b = __float_as_uint(vv[i]);
        h[i] = (ushort)((b + 0x7FFFu + ((b >> 16) & 1u)) >> 16);
    }
    uint4 pk;
    pk.x = (uint)h[0] | ((uint)h[1] << 16);
    pk.y = (uint)h[2] | ((uint)h[3] << 16);
    pk.z = (uint)h[4] | ((uint)h[5] << 16);
    pk.w = (uint)h[6] | ((uint)h[7] << 16);
    ((uint4*)(fb + (size_t)wave * DIM))[lane] = pk;

#pragma unroll
    for (int m = 32; m; m >>= 1) s += __shfl_xor(s, m);
    if (lane == 0) sq[wave] = s;
}

// ---------- kernel 2: flash-style RBF entropy + fused control/scale epilogue ----------
// grid (N/64, B), 512 threads = 8 waves. Wave w: row-strip (w&3)*16, j-half (w>>2).
__global__ __launch_bounds__(512) void entropy_kernel(
    const float* __restrict__ feat, const ushort* __restrict__ fb,
    const float* __restrict__ sq, const float* __restrict__ tgt,
    const float* __restrict__ temp, float* __restrict__ out)
{
    __shared__ char smem_raw[65536];               // Bs (64KB), reused by epilogue
    ushort* Bs = (ushort*)smem_raw;

    const int t     = threadIdx.x;
    const int w     = t >> 6;
    const int lane  = t & 63;
    const int q     = lane >> 4;                   // quad 0..3
    const int c16   = lane & 15;
    const int strip = w & 3;
    const int half  = w >> 2;

    const int batch = blockIdx.y;
    const int ibase = blockIdx.x * 64;
    const size_t rowbase = (size_t)batch * N_TOK;

    const float tau    = temp[0];
    const float inv2t2 = 0.5f / (tau * tau);
    const float target = tgt[0];

    // A fragments for this wave's 16-row strip, all of K, in registers (64 VGPR)
    bf16x8 afrag[16];
    {
        const uint4* ap = (const uint4*)(fb + (rowbase + ibase + strip * 16 + c16) * DIM);
#pragma unroll
        for (int kc = 0; kc < 16; ++kc)
            afrag[kc] = __builtin_bit_cast(bf16x8, ap[kc * 4 + q]);
    }

    float sqi[4];
#pragma unroll
    for (int r = 0; r < 4; ++r)
        sqi[r] = sq[rowbase + ibase + strip * 16 + q * 4 + r];

    float S[4] = {0, 0, 0, 0}, T[4] = {0, 0, 0, 0};
    const int jt0 = half * 2, jt1 = half * 2 + 1;

    for (int jb = 0; jb < N_TOK; jb += 64) {
        __syncthreads();                            // previous Bs reads done
        // stage 64x512 bf16 B-tile; XOR-8 16B-chunk swizzle breaks bank conflicts
#pragma unroll
        for (int i = 0; i < 8; ++i) {
            int fc  = t + i * 512;                  // flat 16B-chunk id, coalesced
            int row = fc >> 6;
            int ch  = fc & 63;
            uint4 val = ((const uint4*)(fb + (rowbase + jb) * DIM))[fc];
            ((uint4*)(Bs + row * DIM))[ch ^ (row & 7)] = val;
        }
        __syncthreads();

        float sqj0 = sq[rowbase + jb + jt0 * 16 + c16];
        float sqj1 = sq[rowbase + jb + jt1 * 16 + c16];

        f32x4 acc0 = {0, 0, 0, 0}, acc1 = {0, 0, 0, 0};
        const int brow0 = jt0 * 16 + c16, brow1 = jt1 * 16 + c16;
        const uint4* b0p = (const uint4*)(Bs + brow0 * DIM);
        const uint4* b1p = (const uint4*)(Bs + brow1 * DIM);
        const int sw0 = brow0 & 7, sw1 = brow1 & 7;
#pragma unroll
        for (int kc = 0; kc < 16; ++kc) {
            bf16x8 b0 = __builtin_bit_cast(bf16x8, b0p[(kc * 4 + q) ^ sw0]);
            bf16x8 b1 = __builtin_bit_cast(bf16x8, b1p[(kc * 4 + q) ^ sw1]);
            acc0 = __builtin_amdgcn_mfma_f32_16x16x32_bf16(afrag[kc], b0, acc0, 0, 0, 0);
            acc1 = __builtin_amdgcn_mfma_f32_16x16x32_bf16(afrag[kc], b1, acc1, 0, 0, 0);
        }
        // k = exp(-d2/(2tau^2));  k*log k = k*e  (no log needed)
#pragma unroll
        for (int r = 0; r < 4; ++r) {
            float d0 = fmaxf(sqi[r] + sqj0 - 2.0f * acc0[r], 0.0f);
            float e0 = -d0 * inv2t2;
            float k0 = __expf(e0);
            S[r] += k0; T[r] += k0 * e0;
            float d1 = fmaxf(sqi[r] + sqj1 - 2.0f * acc1[r], 0.0f);
            float e1 = -d1 * inv2t2;
            float k1 = __expf(e1);
            S[r] += k1; T[r] += k1 * e1;
        }
    }

    // reduce S,T across the 16 columns held in each quad
#pragma unroll
    for (int m = 1; m < 16; m <<= 1) {
#pragma unroll
        for (int r = 0; r < 4; ++r) {
            S[r] += __shfl_xor(S[r], m);
            T[r] += __shfl_xor(T[r], m);
        }
    }

    __syncthreads();                                // Bs dead; reuse LDS
    float* red  = (float*)smem_raw;                 // [2][64][2]
    float* ctrl = (float*)(smem_raw + 1024);        // [64]
    if (c16 == 0) {
#pragma unroll
        for (int r = 0; r < 4; ++r) {
            int row = strip * 16 + q * 4 + r;
            red[(half * 64 + row) * 2 + 0] = S[r];
            red[(half * 64 + row) * 2 + 1] = T[r];
        }
    }
    __syncthreads();
    if (t < 64) {
        float Ss = red[t * 2]     + red[(64 + t) * 2];
        float Ts = red[t * 2 + 1] + red[(64 + t) * 2 + 1];
        float E  = __logf(Ss) - Ts / Ss;            // entropy (sans +1e-6, bias<4e-3)
        float cs = 1.0f / (1.0f + __expf((E - target) / tau));
        ctrl[t] = cs;
        out[(size_t)BATCH * N_TOK * DIM + rowbase + ibase + t] = cs;
    }
    __syncthreads();

    // fused epilogue: controlled_features = features * control[row]
    const float4* F4 = (const float4*)(feat + (rowbase + ibase) * DIM);
    float4*       O4 = (float4*)(out + (rowbase + ibase) * DIM);
#pragma unroll
    for (int it = 0; it < 16; ++it) {
        int idx  = t + it * 512;                    // 8192 float4 = 64 rows x 128
        float cs = ctrl[idx >> 7];
        float4 v = F4[idx];
        v.x *= cs; v.y *= cs; v.z *= cs; v.w *= cs;
        O4[idx] = v;
    }
}

extern "C" void kernel_launch(void* const* d_in, const int* in_sizes, int n_in,
                              void* d_out, int out_size, void* d_ws, size_t ws_size,
                              hipStream_t stream) {
    const float* feat = (const float*)d_in[0];
    const float* tgt  = (const float*)d_in[7];   // target_entropy
    const float* temp = (const float*)d_in[8];   // temperature
    float* out = (float*)d_out;

    ushort* fb = (ushort*)d_ws;                                          // bf16 features
    float*  sq = (float*)((char*)d_ws + (size_t)BATCH * N_TOK * DIM * 2); // row sumsq

    prep_kernel<<<dim3(BATCH * N_TOK / 4), dim3(256), 0, stream>>>(feat, fb, sq);
    entropy_kernel<<<dim3(N_TOK / 64, BATCH), dim3(512), 0, stream>>>(feat, fb, sq, tgt, temp, out);
}

// Round 2
// 272.340 us; speedup vs baseline: 1.1347x; 1.1347x over previous
//
#include <hip/hip_runtime.h>
#include <hip/hip_bf16.h>
#include <stdint.h>

#define N_TOK 4096
#define DIM   512
#define BATCH 4
#define BN    (BATCH * N_TOK)

typedef __attribute__((ext_vector_type(8))) short bf16x8;
typedef __attribute__((ext_vector_type(4))) float f32x4;

// ---------- kernel 1: per-row sum-of-squares (fp32) + fp32->bf16 convert ----------
__global__ __launch_bounds__(256) void prep_kernel(
    const float* __restrict__ feat, ushort* __restrict__ fb, float* __restrict__ sq)
{
    int wave = (blockIdx.x << 2) + (threadIdx.x >> 6);   // row index 0..B*N-1
    int lane = threadIdx.x & 63;
    const float4* src = (const float4*)(feat + (size_t)wave * DIM);
    float4 v0 = src[lane * 2];
    float4 v1 = src[lane * 2 + 1];
    float s = v0.x*v0.x + v0.y*v0.y + v0.z*v0.z + v0.w*v0.w
            + v1.x*v1.x + v1.y*v1.y + v1.z*v1.z + v1.w*v1.w;

    float vv[8] = {v0.x, v0.y, v0.z, v0.w, v1.x, v1.y, v1.z, v1.w};
    ushort h[8];
#pragma unroll
    for (int i = 0; i < 8; ++i) {         // RNE fp32->bf16
        uint32_t b = __float_as_uint(vv[i]);
        h[i] = (ushort)((b + 0x7FFFu + ((b >> 16) & 1u)) >> 16);
    }
    uint4 pk;
    pk.x = (uint)h[0] | ((uint)h[1] << 16);
    pk.y = (uint)h[2] | ((uint)h[3] << 16);
    pk.z = (uint)h[4] | ((uint)h[5] << 16);
    pk.w = (uint)h[6] | ((uint)h[7] << 16);
    ((uint4*)(fb + (size_t)wave * DIM))[lane] = pk;

#pragma unroll
    for (int m = 32; m; m >>= 1) s += __shfl_xor(s, m);
    if (lane == 0) sq[wave] = s;
}

// ---------- kernel 2: flash-style RBF entropy, j-split + double-buffered ----------
// grid (N/64, B, 2): 512 blocks = 2/CU, 512 threads = 8 waves (16 waves/CU).
// Each block: 64 i-rows, half the j-range (2048). B-tiles of 32 rows, 2 LDS bufs.
// Wave w: i-strip (w&3)*16, j-half (w>>2) of each 32-row tile.
__global__ __launch_bounds__(512, 4) void entropy_kernel(
    const ushort* __restrict__ fb, const float* __restrict__ sq,
    const float* __restrict__ temp,
    float* __restrict__ Sp, float* __restrict__ Tp)
{
    __shared__ char smem_raw[65536];               // 2 x 32KB B-tile buffers
    ushort* Bs0 = (ushort*)smem_raw;
    ushort* Bs1 = (ushort*)(smem_raw + 32768);

    const int t     = threadIdx.x;
    const int w     = t >> 6;
    const int lane  = t & 63;
    const int q     = lane >> 4;                   // quad 0..3
    const int c16   = lane & 15;
    const int strip = w & 3;
    const int half  = w >> 2;                      // which 16-row half of B-tile

    const int batch  = blockIdx.y;
    const int ibase  = blockIdx.x * 64;
    const int jh     = blockIdx.z;
    const int jstart = jh * (N_TOK / 2);
    const size_t rowbase = (size_t)batch * N_TOK;

    const float tau    = temp[0];
    const float inv2t2 = 0.5f / (tau * tau);

    // A fragments: this wave's 16 i-rows, all K, in registers (64 VGPR)
    bf16x8 afrag[16];
    {
        const uint4* ap = (const uint4*)(fb + (rowbase + ibase + strip * 16 + c16) * DIM);
#pragma unroll
        for (int kc = 0; kc < 16; ++kc)
            afrag[kc] = __builtin_bit_cast(bf16x8, ap[kc * 4 + q]);
    }
    float sqi[4];
#pragma unroll
    for (int r = 0; r < 4; ++r)
        sqi[r] = sq[rowbase + ibase + strip * 16 + q * 4 + r];

    float S[4] = {0, 0, 0, 0}, T[4] = {0, 0, 0, 0};

    // stage tile 0 into Bs0 (32 rows x 512 bf16 = 2048 uint4; 4 per thread)
    {
        const uint4* src = (const uint4*)(fb + (rowbase + jstart) * DIM);
#pragma unroll
        for (int i = 0; i < 4; ++i) {
            int fc = t + i * 512, row = fc >> 6, ch = fc & 63;
            ((uint4*)(Bs0 + row * DIM))[ch ^ (row & 7)] = src[fc];
        }
    }
    __syncthreads();

    const int brow = half * 16 + c16;              // B-tile row this lane consumes
    const int sw   = brow & 7;
    int cur = 0;

    for (int it = 0; it < 64; ++it) {
        const int jb = jstart + it * 32;
        uint4 pf[4];
        if (it + 1 < 64) {                          // prefetch next tile -> VGPRs
            const uint4* src = (const uint4*)(fb + (rowbase + jb + 32) * DIM);
#pragma unroll
            for (int i = 0; i < 4; ++i) pf[i] = src[t + i * 512];
        }

        float sqj = sq[rowbase + jb + brow];
        const ushort* Bc = cur ? Bs1 : Bs0;
        const uint4* bp = (const uint4*)(Bc + brow * DIM);

        f32x4 accA = {0, 0, 0, 0}, accB = {0, 0, 0, 0};   // ILP=2 chains
#pragma unroll
        for (int kc = 0; kc < 16; kc += 2) {
            bf16x8 b0 = __builtin_bit_cast(bf16x8, bp[(kc * 4 + q) ^ sw]);
            bf16x8 b1 = __builtin_bit_cast(bf16x8, bp[((kc + 1) * 4 + q) ^ sw]);
            accA = __builtin_amdgcn_mfma_f32_16x16x32_bf16(afrag[kc],     b0, accA, 0, 0, 0);
            accB = __builtin_amdgcn_mfma_f32_16x16x32_bf16(afrag[kc + 1], b1, accB, 0, 0, 0);
        }

#pragma unroll
        for (int r = 0; r < 4; ++r) {
            float g = accA[r] + accB[r];
            float d = fmaxf(sqi[r] + sqj - 2.0f * g, 0.0f);
            float e = -d * inv2t2;
            float k = __expf(e);
            S[r] += k; T[r] += k * e;
        }

        if (it + 1 < 64) {                          // store prefetch -> other buffer
            ushort* Bn = cur ? Bs0 : Bs1;
#pragma unroll
            for (int i = 0; i < 4; ++i) {
                int fc = t + i * 512, row = fc >> 6, ch = fc & 63;
                ((uint4*)(Bn + row * DIM))[ch ^ (row & 7)] = pf[i];
            }
        }
        __syncthreads();
        cur ^= 1;
    }

    // reduce S,T across the 16 j-columns each quad holds
#pragma unroll
    for (int m = 1; m < 16; m <<= 1) {
#pragma unroll
        for (int r = 0; r < 4; ++r) {
            S[r] += __shfl_xor(S[r], m);
            T[r] += __shfl_xor(T[r], m);
        }
    }

    float* redS = (float*)smem_raw;                // [2][64], reuse dead B-tile LDS
    float* redT = (float*)(smem_raw + 512 * 4);
    if (c16 == 0) {
#pragma unroll
        for (int r = 0; r < 4; ++r) {
            int row = strip * 16 + q * 4 + r;
            redS[half * 64 + row] = S[r];
            redT[half * 64 + row] = T[r];
        }
    }
    __syncthreads();
    if (t < 64) {                                  // combine j-halves of this block
        size_t grow = rowbase + ibase + t;
        Sp[(size_t)jh * BN + grow] = redS[t] + redS[64 + t];
        Tp[(size_t)jh * BN + grow] = redT[t] + redT[64 + t];
    }
}

// ---------- kernel 3: combine partials, entropy -> sigmoid -> scale features ----------
__global__ __launch_bounds__(256) void finalize_kernel(
    const float* __restrict__ feat, const float* __restrict__ Sp,
    const float* __restrict__ Tp, const float* __restrict__ tgt,
    const float* __restrict__ temp, float* __restrict__ out)
{
    int row  = (blockIdx.x << 2) + (threadIdx.x >> 6);   // global row 0..B*N-1
    int lane = threadIdx.x & 63;
    float S = Sp[row] + Sp[BN + row];
    float T = Tp[row] + Tp[BN + row];
    float tau = temp[0];
    float E  = __logf(S) - T / S;                  // entropy (sans +1e-6, bias<4e-3)
    float cs = 1.0f / (1.0f + __expf((E - tgt[0]) / tau));

    const float4* F4 = (const float4*)(feat + (size_t)row * DIM);
    float4*       O4 = (float4*)(out + (size_t)row * DIM);
    float4 v0 = F4[lane], v1 = F4[lane + 64];
    v0.x *= cs; v0.y *= cs; v0.z *= cs; v0.w *= cs;
    v1.x *= cs; v1.y *= cs; v1.z *= cs; v1.w *= cs;
    O4[lane] = v0; O4[lane + 64] = v1;
    if (lane == 0) out[(size_t)BN * DIM + row] = cs;
}

extern "C" void kernel_launch(void* const* d_in, const int* in_sizes, int n_in,
                              void* d_out, int out_size, void* d_ws, size_t ws_size,
                              hipStream_t stream) {
    const float* feat = (const float*)d_in[0];
    const float* tgt  = (const float*)d_in[7];   // target_entropy
    const float* temp = (const float*)d_in[8];   // temperature
    float* out = (float*)d_out;

    char* ws = (char*)d_ws;
    ushort* fb = (ushort*)ws;                                  // bf16 features, 16.8MB
    float*  sq = (float*)(ws + (size_t)BN * DIM * 2);          // row sumsq, 64KB
    float*  Sp = (float*)(ws + (size_t)BN * DIM * 2 + BN * 4); // partial S, 2 halves
    float*  Tp = Sp + 2 * BN;                                  // partial T, 2 halves

    prep_kernel<<<dim3(BN / 4), dim3(256), 0, stream>>>(feat, fb, sq);
    entropy_kernel<<<dim3(N_TOK / 64, BATCH, 2), dim3(512), 0, stream>>>(fb, sq, temp, Sp, Tp);
    finalize_kernel<<<dim3(BN / 4), dim3(256), 0, stream>>>(feat, Sp, Tp, tgt, temp, out);
}

// Round 3
// 176.159 us; speedup vs baseline: 1.7543x; 1.5460x over previous
//
#include <hip/hip_runtime.h>
#include <hip/hip_bf16.h>
#include <stdint.h>

#define N_TOK 4096
#define DIM   512
#define BATCH 4
#define BN    (BATCH * N_TOK)
#define JSPLIT 4

typedef __attribute__((ext_vector_type(8))) short bf16x8;
typedef __attribute__((ext_vector_type(4))) float f32x4;

// ---------- kernel 1: per-row sum-of-squares (fp32) + fp32->bf16 convert ----------
__global__ __launch_bounds__(256) void prep_kernel(
    const float* __restrict__ feat, ushort* __restrict__ fb, float* __restrict__ sq)
{
    int wave = (blockIdx.x << 2) + (threadIdx.x >> 6);   // row index 0..B*N-1
    int lane = threadIdx.x & 63;
    const float4* src = (const float4*)(feat + (size_t)wave * DIM);
    float4 v0 = src[lane * 2];
    float4 v1 = src[lane * 2 + 1];
    float s = v0.x*v0.x + v0.y*v0.y + v0.z*v0.z + v0.w*v0.w
            + v1.x*v1.x + v1.y*v1.y + v1.z*v1.z + v1.w*v1.w;

    float vv[8] = {v0.x, v0.y, v0.z, v0.w, v1.x, v1.y, v1.z, v1.w};
    ushort h[8];
#pragma unroll
    for (int i = 0; i < 8; ++i) {         // RNE fp32->bf16
        uint32_t b = __float_as_uint(vv[i]);
        h[i] = (ushort)((b + 0x7FFFu + ((b >> 16) & 1u)) >> 16);
    }
    uint4 pk;
    pk.x = (uint)h[0] | ((uint)h[1] << 16);
    pk.y = (uint)h[2] | ((uint)h[3] << 16);
    pk.z = (uint)h[4] | ((uint)h[5] << 16);
    pk.w = (uint)h[6] | ((uint)h[7] << 16);
    ((uint4*)(fb + (size_t)wave * DIM))[lane] = pk;

#pragma unroll
    for (int m = 32; m; m >>= 1) s += __shfl_xor(s, m);
    if (lane == 0) sq[wave] = s;
}

// async global->LDS of one 1KB row with XOR-8 chunk swizzle done on the GLOBAL side:
// lane i lands at lrow + i*16 and carries global chunk (i ^ swz).
__device__ __forceinline__ void async_row(const ushort* grow, ushort* lrow, int lane, int swz)
{
    const uint4* gsrc = (const uint4*)grow + (lane ^ swz);
    __builtin_amdgcn_global_load_lds(
        (const __attribute__((address_space(1))) void*)gsrc,
        (__attribute__((address_space(3))) void*)lrow, 16, 0, 0);
}

// ---------- kernel 2: flash-style RBF entropy ----------
// grid (N/128, B, JSPLIT) = 512 blocks (2/CU), 256 threads = 4 waves.
// Each wave: 32 i-rows (2 strips, A resident in 128 VGPR), sweeps full 32-row
// j-tiles => 4 MFMAs per B-fragment read (16 MACs/LDS-byte).
__global__ __launch_bounds__(256, 2) void entropy_kernel(
    const ushort* __restrict__ fb, const float* __restrict__ sq,
    const float* __restrict__ temp,
    float* __restrict__ Sp, float* __restrict__ Tp)
{
    __shared__ __align__(16) ushort Bs[2][32 * DIM];     // 2 x 32KB double buffer

    const int t    = threadIdx.x;
    const int w    = t >> 6;
    const int lane = t & 63;
    const int q    = lane >> 4;
    const int c16  = lane & 15;

    const int batch  = blockIdx.y;
    const int jh     = blockIdx.z;
    const int ibase  = blockIdx.x * 128;
    const int iw     = ibase + w * 32;                   // this wave's 32 i-rows
    const int jstart = jh * (N_TOK / JSPLIT);
    const size_t rowbase = (size_t)batch * N_TOK;

    const float tau    = temp[0];
    const float n2t2   = -0.5f / (tau * tau);

    // A fragments: 2 strips x 16 k-chunks, resident (128 VGPR)
    bf16x8 afrag[2][16];
#pragma unroll
    for (int s = 0; s < 2; ++s) {
        const uint4* ap = (const uint4*)(fb + (rowbase + iw + s * 16 + c16) * DIM);
#pragma unroll
        for (int kc = 0; kc < 16; ++kc)
            afrag[s][kc] = __builtin_bit_cast(bf16x8, ap[kc * 4 + q]);
    }
    float sqi[2][4];
#pragma unroll
    for (int s = 0; s < 2; ++s)
#pragma unroll
        for (int r = 0; r < 4; ++r)
            sqi[s][r] = sq[rowbase + iw + s * 16 + q * 4 + r];

    float S[2][4] = {{0,0,0,0},{0,0,0,0}}, T[2][4] = {{0,0,0,0},{0,0,0,0}};

    // stage tile 0 (each wave DMAs 8 rows)
#pragma unroll
    for (int rr = 0; rr < 8; ++rr) {
        int row = w * 8 + rr;
        async_row(fb + (rowbase + jstart + row) * DIM, &Bs[0][row * DIM], lane, row & 7);
    }
    __syncthreads();

    const int sw = c16 & 7;                              // rows c16 and 16+c16 share swizzle
    int cur = 0;
    for (int it = 0; it < N_TOK / JSPLIT / 32; ++it) {
        const int jb = jstart + it * 32;
        if (it + 1 < N_TOK / JSPLIT / 32) {              // async-prefetch next tile
#pragma unroll
            for (int rr = 0; rr < 8; ++rr) {
                int row = w * 8 + rr;
                async_row(fb + (rowbase + jb + 32 + row) * DIM,
                          &Bs[cur ^ 1][row * DIM], lane, row & 7);
            }
        }

        float sqj0 = sq[rowbase + jb + c16];
        float sqj1 = sq[rowbase + jb + 16 + c16];
        const uint4* b0p = (const uint4*)(&Bs[cur][c16 * DIM]);
        const uint4* b1p = (const uint4*)(&Bs[cur][(16 + c16) * DIM]);

        f32x4 a00 = {0,0,0,0}, a01 = {0,0,0,0}, a10 = {0,0,0,0}, a11 = {0,0,0,0};
#pragma unroll
        for (int kc = 0; kc < 16; ++kc) {
            bf16x8 b0 = __builtin_bit_cast(bf16x8, b0p[(kc * 4 + q) ^ sw]);
            bf16x8 b1 = __builtin_bit_cast(bf16x8, b1p[(kc * 4 + q) ^ sw]);
            a00 = __builtin_amdgcn_mfma_f32_16x16x32_bf16(afrag[0][kc], b0, a00, 0, 0, 0);
            a01 = __builtin_amdgcn_mfma_f32_16x16x32_bf16(afrag[0][kc], b1, a01, 0, 0, 0);
            a10 = __builtin_amdgcn_mfma_f32_16x16x32_bf16(afrag[1][kc], b0, a10, 0, 0, 0);
            a11 = __builtin_amdgcn_mfma_f32_16x16x32_bf16(afrag[1][kc], b1, a11, 0, 0, 0);
        }

#pragma unroll
        for (int r = 0; r < 4; ++r) {
            float d, e, k;
            d = fmaxf(sqi[0][r] + sqj0 - 2.0f * a00[r], 0.0f);
            e = d * n2t2; k = __expf(e); S[0][r] += k; T[0][r] = fmaf(k, e, T[0][r]);
            d = fmaxf(sqi[0][r] + sqj1 - 2.0f * a01[r], 0.0f);
            e = d * n2t2; k = __expf(e); S[0][r] += k; T[0][r] = fmaf(k, e, T[0][r]);
            d = fmaxf(sqi[1][r] + sqj0 - 2.0f * a10[r], 0.0f);
            e = d * n2t2; k = __expf(e); S[1][r] += k; T[1][r] = fmaf(k, e, T[1][r]);
            d = fmaxf(sqi[1][r] + sqj1 - 2.0f * a11[r], 0.0f);
            e = d * n2t2; k = __expf(e); S[1][r] += k; T[1][r] = fmaf(k, e, T[1][r]);
        }
        __syncthreads();                                 // nxt DMA landed; cur reads done
        cur ^= 1;
    }

    // reduce over the 16 j-columns each lane group holds (c16 dimension)
#pragma unroll
    for (int m = 1; m < 16; m <<= 1)
#pragma unroll
        for (int s = 0; s < 2; ++s)
#pragma unroll
            for (int r = 0; r < 4; ++r) {
                S[s][r] += __shfl_xor(S[s][r], m);
                T[s][r] += __shfl_xor(T[s][r], m);
            }

    if (c16 == 0) {                                      // each wave owns its i-rows
#pragma unroll
        for (int s = 0; s < 2; ++s)
#pragma unroll
            for (int r = 0; r < 4; ++r) {
                size_t idx = (size_t)jh * BN + rowbase + iw + s * 16 + q * 4 + r;
                Sp[idx] = S[s][r];
                Tp[idx] = T[s][r];
            }
    }
}

// ---------- kernel 3: combine partials, entropy -> sigmoid -> scale features ----------
__global__ __launch_bounds__(256) void finalize_kernel(
    const float* __restrict__ feat, const float* __restrict__ Sp,
    const float* __restrict__ Tp, const float* __restrict__ tgt,
    const float* __restrict__ temp, float* __restrict__ out)
{
    int row  = (blockIdx.x << 2) + (threadIdx.x >> 6);   // global row 0..B*N-1
    int lane = threadIdx.x & 63;
    float S = 0.0f, T = 0.0f;
#pragma unroll
    for (int j = 0; j < JSPLIT; ++j) {
        S += Sp[(size_t)j * BN + row];
        T += Tp[(size_t)j * BN + row];
    }
    float tau = temp[0];
    float E  = __logf(S) - T / S;                  // entropy (sans +1e-6, bias<4e-3)
    float cs = 1.0f / (1.0f + __expf((E - tgt[0]) / tau));

    const float4* F4 = (const float4*)(feat + (size_t)row * DIM);
    float4*       O4 = (float4*)(out + (size_t)row * DIM);
    float4 v0 = F4[lane], v1 = F4[lane + 64];
    v0.x *= cs; v0.y *= cs; v0.z *= cs; v0.w *= cs;
    v1.x *= cs; v1.y *= cs; v1.z *= cs; v1.w *= cs;
    O4[lane] = v0; O4[lane + 64] = v1;
    if (lane == 0) out[(size_t)BN * DIM + row] = cs;
}

extern "C" void kernel_launch(void* const* d_in, const int* in_sizes, int n_in,
                              void* d_out, int out_size, void* d_ws, size_t ws_size,
                              hipStream_t stream) {
    const float* feat = (const float*)d_in[0];
    const float* tgt  = (const float*)d_in[7];   // target_entropy
    const float* temp = (const float*)d_in[8];   // temperature
    float* out = (float*)d_out;

    char* ws = (char*)d_ws;
    ushort* fb = (ushort*)ws;                                  // bf16 features, 16.8MB
    float*  sq = (float*)(ws + (size_t)BN * DIM * 2);          // row sumsq, 64KB
    float*  Sp = (float*)(ws + (size_t)BN * DIM * 2 + BN * 4); // partial S, JSPLIT slices
    float*  Tp = Sp + (size_t)JSPLIT * BN;                     // partial T, JSPLIT slices

    prep_kernel<<<dim3(BN / 4), dim3(256), 0, stream>>>(feat, fb, sq);
    entropy_kernel<<<dim3(N_TOK / 128, BATCH, JSPLIT), dim3(256), 0, stream>>>(fb, sq, temp, Sp, Tp);
    finalize_kernel<<<dim3(BN / 4), dim3(256), 0, stream>>>(feat, Sp, Tp, tgt, temp, out);
}

// Round 5
// 169.736 us; speedup vs baseline: 1.8207x; 1.0378x over previous
//
#include <hip/hip_runtime.h>
#include <stdint.h>

#define N_TOK 4096
#define DIM   512
#define BATCH 4
#define BN    (BATCH * N_TOK)
#define JSPLIT 8
#define JT    32                      // j-tile rows
#define IPW   64                      // i-rows per wave
#define IPB   256                     // i-rows per block (4 waves)
#define JITERS (N_TOK / JSPLIT / JT)  // 16

typedef __attribute__((ext_vector_type(4))) float f32x4;

// ---------- kernel 1: fp32 -> fp8(e4m3) convert + per-row sumsq of QUANTIZED values ----------
// sq from quantized values => diagonal d_ii ~ 0 exactly, matching ref's k_ii = 1.
__global__ __launch_bounds__(256) void prep_kernel(
    const float* __restrict__ feat, uint8_t* __restrict__ fb, float* __restrict__ sq)
{
    int row  = (blockIdx.x << 2) + (threadIdx.x >> 6);   // 0..BN-1
    int lane = threadIdx.x & 63;
    const float4* src = (const float4*)(feat + (size_t)row * DIM);
    float4 v0 = src[lane * 2];
    float4 v1 = src[lane * 2 + 1];

    uint w01 = (uint)__builtin_amdgcn_cvt_pk_fp8_f32(v0.x, v0.y, 0, false);
    w01      = (uint)__builtin_amdgcn_cvt_pk_fp8_f32(v0.z, v0.w, (int)w01, true);
    uint w23 = (uint)__builtin_amdgcn_cvt_pk_fp8_f32(v1.x, v1.y, 0, false);
    w23      = (uint)__builtin_amdgcn_cvt_pk_fp8_f32(v1.z, v1.w, (int)w23, true);
    uint2 pk; pk.x = w01; pk.y = w23;
    ((uint2*)(fb + (size_t)row * DIM))[lane] = pk;

    float s = 0.f, f;
    f = __builtin_amdgcn_cvt_f32_fp8((int)w01, 0); s = fmaf(f, f, s);
    f = __builtin_amdgcn_cvt_f32_fp8((int)w01, 1); s = fmaf(f, f, s);
    f = __builtin_amdgcn_cvt_f32_fp8((int)w01, 2); s = fmaf(f, f, s);
    f = __builtin_amdgcn_cvt_f32_fp8((int)w01, 3); s = fmaf(f, f, s);
    f = __builtin_amdgcn_cvt_f32_fp8((int)w23, 0); s = fmaf(f, f, s);
    f = __builtin_amdgcn_cvt_f32_fp8((int)w23, 1); s = fmaf(f, f, s);
    f = __builtin_amdgcn_cvt_f32_fp8((int)w23, 2); s = fmaf(f, f, s);
    f = __builtin_amdgcn_cvt_f32_fp8((int)w23, 3); s = fmaf(f, f, s);

#pragma unroll
    for (int m = 32; m; m >>= 1) s += __shfl_xor(s, m);
    if (lane == 0) sq[row] = s;
}

// async DMA of a 2-row pair (2 x 512B) with XOR-8 16B-chunk swizzle on the GLOBAL side.
__device__ __forceinline__ void dma2(const uint8_t* g, uint8_t* l, int lane, int r)
{
    int loc = lane & 31, h = lane >> 5;
    int sw  = (r + h) & 7;
    const uint8_t* src = g + h * DIM + ((loc ^ sw) << 4);
    __builtin_amdgcn_global_load_lds(
        (const __attribute__((address_space(1))) void*)src,
        (__attribute__((address_space(3))) void*)l, 16, 0, 0);
}

// ---------- kernel 2: flash-style RBF entropy, fp8 MFMA ----------
// grid (N/256, B, 8) = 512 blocks (2/CU), 256 thr = 4 waves.
// Wave: 64 i-rows resident (4 strips, 128 VGPR fp8 A), sweeps 32-row j-tiles
// => 64 MACs per LDS byte.  e = min(g/tau^2 - (sqi+sqj)/(2 tau^2), 0); k=exp(e).
__global__ __launch_bounds__(256, 2) void entropy_kernel(
    const uint8_t* __restrict__ fb, const float* __restrict__ sq,
    const float* __restrict__ temp,
    float* __restrict__ Sp, float* __restrict__ Tp)
{
    __shared__ __align__(16) uint8_t Bs[2][JT * DIM];    // 2 x 16KB double buffer

    const int t    = threadIdx.x;
    const int w    = t >> 6;
    const int lane = t & 63;
    const int q    = lane >> 4;
    const int c16  = lane & 15;
    const int q1   = q & 1, q2 = q >> 1;
    const int s8   = c16 & 7;

    const int batch  = blockIdx.y;
    const int jh     = blockIdx.z;
    const int iw     = blockIdx.x * IPB + w * IPW;
    const int jstart = jh * (N_TOK / JSPLIT);
    const size_t rowbase = (size_t)batch * N_TOK;

    const float tau    = temp[0];
    const float inv2t2 = 0.5f / (tau * tau);
    const float cg     = 1.0f / (tau * tau);

    // A fragments: 4 strips x 16 k-chunks, 8B fp8 each = 128 VGPR
    long afrag[4][16];
#pragma unroll
    for (int s = 0; s < 4; ++s) {
        const uint2* ap = (const uint2*)(fb + (rowbase + iw + s * 16 + c16) * DIM);
#pragma unroll
        for (int kc = 0; kc < 16; ++kc) {
            uint2 v = ap[kc * 4 + q];
            afrag[s][kc] = (long)(((unsigned long long)v.y << 32) | v.x);
        }
    }
    float pi[4][4];
#pragma unroll
    for (int s = 0; s < 4; ++s)
#pragma unroll
        for (int r = 0; r < 4; ++r)
            pi[s][r] = -sq[rowbase + iw + s * 16 + q * 4 + r] * inv2t2;

    float S[4][4], T[4][4];
#pragma unroll
    for (int s = 0; s < 4; ++s)
#pragma unroll
        for (int r = 0; r < 4; ++r) { S[s][r] = 0.f; T[s][r] = 0.f; }

    // stage tile 0 (each wave DMAs 4 row-pairs)
#pragma unroll
    for (int rr = 0; rr < 4; ++rr) {
        int r = w * 8 + rr * 2;
        dma2(fb + (rowbase + jstart + r) * DIM, &Bs[0][r * DIM], lane, r);
    }
    __syncthreads();

    int cur = 0;
    for (int it = 0; it < JITERS; ++it) {
        const int jb = jstart + it * JT;
        if (it + 1 < JITERS) {                            // async prefetch next tile
#pragma unroll
            for (int rr = 0; rr < 4; ++rr) {
                int r = w * 8 + rr * 2;
                dma2(fb + (rowbase + jb + JT + r) * DIM, &Bs[cur ^ 1][r * DIM], lane, r);
            }
        }
        float pj0 = -sq[rowbase + jb + c16] * inv2t2;
        float pj1 = -sq[rowbase + jb + 16 + c16] * inv2t2;

#pragma unroll
        for (int jsub = 0; jsub < 2; ++jsub) {
            const uint8_t* Brow = &Bs[cur][(jsub * 16 + c16) * DIM] + (q1 << 3);
            f32x4 acc[4] = {{0,0,0,0},{0,0,0,0},{0,0,0,0},{0,0,0,0}};
#pragma unroll
            for (int kc = 0; kc < 16; ++kc) {
                int off = ((kc * 2 + q2) ^ s8) << 4;      // phys 16B chunk, +q1*8 in Brow
                long b  = *(const long*)(Brow + off);
#pragma unroll
                for (int s = 0; s < 4; ++s)
                    acc[s] = __builtin_amdgcn_mfma_f32_16x16x32_fp8_fp8(
                                 afrag[s][kc], b, acc[s], 0, 0, 0);
            }
            float pj = jsub ? pj1 : pj0;
#pragma unroll
            for (int s = 0; s < 4; ++s)
#pragma unroll
                for (int r = 0; r < 4; ++r) {
                    float e = fminf(fmaf(acc[s][r], cg, pi[s][r] + pj), 0.f);
                    float k = __expf(e);
                    S[s][r] += k;
                    T[s][r] = fmaf(k, e, T[s][r]);
                }
        }
        __syncthreads();                                  // prefetch landed; cur reads done
        cur ^= 1;
    }

    // reduce over the 16 j-columns (c16 lanes)
#pragma unroll
    for (int m = 1; m < 16; m <<= 1)
#pragma unroll
        for (int s = 0; s < 4; ++s)
#pragma unroll
            for (int r = 0; r < 4; ++r) {
                S[s][r] += __shfl_xor(S[s][r], m);
                T[s][r] += __shfl_xor(T[s][r], m);
            }

    if (c16 == 0) {
#pragma unroll
        for (int s = 0; s < 4; ++s)
#pragma unroll
            for (int r = 0; r < 4; ++r) {
                size_t idx = (size_t)jh * BN + rowbase + iw + s * 16 + q * 4 + r;
                Sp[idx] = S[s][r];
                Tp[idx] = T[s][r];
            }
    }
}

// ---------- kernel 3: combine partials, entropy -> sigmoid -> scale features ----------
__global__ __launch_bounds__(256) void finalize_kernel(
    const float* __restrict__ feat, const float* __restrict__ Sp,
    const float* __restrict__ Tp, const float* __restrict__ tgt,
    const float* __restrict__ temp, float* __restrict__ out)
{
    int row  = (blockIdx.x << 2) + (threadIdx.x >> 6);   // global row 0..BN-1
    int lane = threadIdx.x & 63;
    float S = 0.0f, T = 0.0f;
#pragma unroll
    for (int j = 0; j < JSPLIT; ++j) {
        S += Sp[(size_t)j * BN + row];
        T += Tp[(size_t)j * BN + row];
    }
    float tau = temp[0];
    float E  = __logf(S) - T / S;                  // entropy (sans +1e-6, bias<4e-3)
    float cs = 1.0f / (1.0f + __expf((E - tgt[0]) / tau));

    const float4* F4 = (const float4*)(feat + (size_t)row * DIM);
    float4*       O4 = (float4*)(out + (size_t)row * DIM);
    float4 v0 = F4[lane], v1 = F4[lane + 64];
    v0.x *= cs; v0.y *= cs; v0.z *= cs; v0.w *= cs;
    v1.x *= cs; v1.y *= cs; v1.z *= cs; v1.w *= cs;
    O4[lane] = v0; O4[lane + 64] = v1;
    if (lane == 0) out[(size_t)BN * DIM + row] = cs;
}

extern "C" void kernel_launch(void* const* d_in, const int* in_sizes, int n_in,
                              void* d_out, int out_size, void* d_ws, size_t ws_size,
                              hipStream_t stream) {
    const float* feat = (const float*)d_in[0];
    const float* tgt  = (const float*)d_in[7];   // target_entropy
    const float* temp = (const float*)d_in[8];   // temperature
    float* out = (float*)d_out;

    char* ws = (char*)d_ws;
    uint8_t* fb = (uint8_t*)ws;                              // fp8 features, 8.4MB
    float*   sq = (float*)(ws + (size_t)BN * DIM);           // quantized row sumsq, 64KB
    float*   Sp = (float*)(ws + (size_t)BN * DIM + BN * 4);  // partial S, JSPLIT slices
    float*   Tp = Sp + (size_t)JSPLIT * BN;                  // partial T, JSPLIT slices

    prep_kernel<<<dim3(BN / 4), dim3(256), 0, stream>>>(feat, fb, sq);
    entropy_kernel<<<dim3(N_TOK / IPB, BATCH, JSPLIT), dim3(256), 0, stream>>>(fb, sq, temp, Sp, Tp);
    finalize_kernel<<<dim3(BN / 4), dim3(256), 0, stream>>>(feat, Sp, Tp, tgt, temp, out);
}